// Round 4
// baseline (822.443 us; speedup 1.0000x reference)
//
#include <hip/hip_runtime.h>

typedef float v2f __attribute__((ext_vector_type(2)));
typedef float v4f __attribute__((ext_vector_type(4)));

#define T_LEN 512
#define INP 5
#define HID 32

__device__ __forceinline__ v2f pkfma(v2f a, v2f b, v2f c) {
    return __builtin_elementwise_fma(a, b, c);
}

// 2 waves per batch element, ONE gate row per lane (row r = tid, 0..127).
//   wave0: rows 0-63   = i[0:32], f[0:32]   (both sigmoid)
//   wave1: rows 64-127 = g[0:32] (tanh), o[0:32] (sigmoid)
// Per-lane weights: Whh0 row (32) + Wih1 row (32) + Whh1 row (32) + Wih0 row (5) ~= 101 f32.
// Step schedule (4 barriers):
//   S1: both: L0 gate = Whh0·h0_{t-1} + Wih0·x_t + b0; act. wave1 -> ab0.
//   B1
//   S3: wave0: shfl i/f pair; lanes<32: cell0 -> h0_t -> hcat[0:32].
//       both: partial = Whh1·h1_{t-1}  (hcat[32:64] still old; disjoint from wave0's write)
//   B2
//   S5: both: L1 gate = Wih1·h0_t + partial + b1; act. wave0 -> ab1.
//   B3
//   S7: wave1: shfl g/o pair; lanes<32: cell1 -> h1_t -> hcat[32:64].
//   B4
__global__ __launch_bounds__(128, 3) void lstm2_2w(
    const float* __restrict__ x,
    const float* __restrict__ Wih0, const float* __restrict__ Whh0,
    const float* __restrict__ bih0, const float* __restrict__ bhh0,
    const float* __restrict__ Wih1, const float* __restrict__ Whh1,
    const float* __restrict__ bih1, const float* __restrict__ bhh1,
    const float* __restrict__ Wfc,  const float* __restrict__ bfc,
    float* __restrict__ out)
{
    const int b   = blockIdx.x;
    const int tid = threadIdx.x;   // gate row r = tid
    const int wid = tid >> 6;      // 0: i,f   1: g,o
    const int l   = tid & 63;
    const int m   = l & 31;        // hidden index

    __shared__ __align__(16) float xs[T_LEN][8];   // 16 KB staged x[b]
    __shared__ __align__(16) float hcat[64];       // [0:32]=h0, [32:64]=h1
    __shared__ __align__(16) float ab0[64];        // wave1's L0 acts: g at [m], o at [32+m]
    __shared__ __align__(16) float ab1[64];        // wave0's L1 acts: i at [m], f at [32+m]

    // ---- stage x[b] into LDS (coalesced-ish, once) ----
    const float* xb = x + (size_t)b * (T_LEN * INP);
    for (int idx = tid; idx < T_LEN * INP; idx += 128) {
        const int t = idx / INP;
        const int d = idx - t * INP;
        xs[t][d] = xb[idx];
    }
    if (tid < 64) hcat[tid] = 0.0f;

    // ---- per-lane weight row (row r of each matrix) ----
    v2f w0[16], wi1[16], wh1[16];
    {
        const v4f* p0 = (const v4f*)(Whh0 + tid * HID);
        const v4f* p1 = (const v4f*)(Wih1 + tid * HID);
        const v4f* p2 = (const v4f*)(Whh1 + tid * HID);
        #pragma unroll
        for (int q = 0; q < 8; ++q) {
            v4f a_ = p0[q], b_ = p1[q], c_ = p2[q];
            w0 [2*q] = __builtin_shufflevector(a_, a_, 0, 1); w0 [2*q+1] = __builtin_shufflevector(a_, a_, 2, 3);
            wi1[2*q] = __builtin_shufflevector(b_, b_, 0, 1); wi1[2*q+1] = __builtin_shufflevector(b_, b_, 2, 3);
            wh1[2*q] = __builtin_shufflevector(c_, c_, 0, 1); wh1[2*q+1] = __builtin_shufflevector(c_, c_, 2, 3);
        }
    }
    v2f wx01, wx23;
    float wx4;
    {
        const float* rl = Wih0 + tid * INP;
        wx01 = (v2f){rl[0], rl[1]}; wx23 = (v2f){rl[2], rl[3]}; wx4 = rl[4];
    }
    const float bias0 = bih0[tid] + bhh0[tid];
    const float bias1 = bih1[tid] + bhh1[tid];

    // own-gate activation constants: sigmoid everywhere except wave1 lanes<32 (g: tanh)
    //   act(v) = sc * rcp(1 + exp2(kk*v)) + bb
    const float NL2E  = -1.4426950408889634f;
    const float NL2E2 = -2.8853900817779268f;
    const bool tanhg = (wid == 1) && (l < 32);
    const float kk = tanhg ? NL2E2 : NL2E;
    const float sc = tanhg ?  2.0f : 1.0f;
    const float bb = tanhg ? -1.0f : 0.0f;

    float cst = 0.0f;     // c0 in wave0 lanes<32 ; c1 in wave1 lanes<32
    float hlast = 0.0f;   // wave1 lanes<32: running h1

    __syncthreads();

    const v4f* h4 = (const v4f*)hcat;   // quads 0..7 = h0, 8..15 = h1

#define RED4(a0,a1,a2,a3) ({ v2f s_ = ((a0)+(a1)) + ((a2)+(a3)); s_.x + s_.y; })

    for (int t = 0; t < T_LEN; ++t) {
        // ---------------- S1: layer-0 gate ----------------
        v4f xq = *(const v4f*)&xs[t][0];
        const float x4 = xs[t][4];
        v2f a0 = pkfma(wx01, (v2f){xq.x, xq.y}, (v2f){bias0, 0.0f});
        v2f a1 = pkfma(wx23, (v2f){xq.z, xq.w}, (v2f){wx4 * x4, 0.0f});
        v2f a2 = (v2f)0.0f, a3 = (v2f)0.0f;
        #pragma unroll
        for (int q = 0; q < 4; ++q) {          // h0 quads 0..3 -> 8 v2f
            v4f hq = h4[q];
            v2f hp0 = __builtin_shufflevector(hq, hq, 0, 1);
            v2f hp1 = __builtin_shufflevector(hq, hq, 2, 3);
            a0 = pkfma(w0[2*q],   hp0, a0);
            a1 = pkfma(w0[2*q+1], hp1, a1);
        }
        #pragma unroll
        for (int q = 4; q < 8; ++q) {
            v4f hq = h4[q];
            v2f hp0 = __builtin_shufflevector(hq, hq, 0, 1);
            v2f hp1 = __builtin_shufflevector(hq, hq, 2, 3);
            a2 = pkfma(w0[2*q],   hp0, a2);
            a3 = pkfma(w0[2*q+1], hp1, a3);
        }
        float g0 = RED4(a0, a1, a2, a3);
        float act0 = fmaf(sc, __builtin_amdgcn_rcpf(1.0f + exp2f(kk * g0)), bb);
        if (wid == 1) ab0[l] = act0;           // g -> [m], o -> [32+m]
        __syncthreads();                        // B1

        // ---------------- S3: cell0 (wave0) + Whh1·h1_old partial (both) ----------------
        if (wid == 0) {
            float fv = __shfl_xor(act0, 32);    // lanes<32: f[m]
            if (l < 32) {
                float gv = ab0[m], ov = ab0[32 + m];
                cst = fmaf(fv, cst, act0 * gv);            // c0 = f*c0 + i*g
                float th = fmaf(2.0f, __builtin_amdgcn_rcpf(1.0f + exp2f(NL2E2 * cst)), -1.0f);
                hcat[m] = ov * th;                         // h0_t
            }
        }
        v2f p0 = (v2f){bias1, 0.0f}, p1 = (v2f)0.0f, p2 = (v2f)0.0f, p3 = (v2f)0.0f;
        #pragma unroll
        for (int q = 0; q < 4; ++q) {          // h1_old quads 8..11
            v4f hq = h4[8 + q];
            v2f hp0 = __builtin_shufflevector(hq, hq, 0, 1);
            v2f hp1 = __builtin_shufflevector(hq, hq, 2, 3);
            p0 = pkfma(wh1[2*q],   hp0, p0);
            p1 = pkfma(wh1[2*q+1], hp1, p1);
        }
        #pragma unroll
        for (int q = 4; q < 8; ++q) {          // h1_old quads 12..15
            v4f hq = h4[8 + q];
            v2f hp0 = __builtin_shufflevector(hq, hq, 0, 1);
            v2f hp1 = __builtin_shufflevector(hq, hq, 2, 3);
            p2 = pkfma(wh1[2*q],   hp0, p2);
            p3 = pkfma(wh1[2*q+1], hp1, p3);
        }
        __syncthreads();                        // B2 (h0_t visible)

        // ---------------- S5: layer-1 gate ----------------
        #pragma unroll
        for (int q = 0; q < 4; ++q) {          // h0_t quads 0..3
            v4f hq = h4[q];
            v2f hp0 = __builtin_shufflevector(hq, hq, 0, 1);
            v2f hp1 = __builtin_shufflevector(hq, hq, 2, 3);
            p0 = pkfma(wi1[2*q],   hp0, p0);
            p1 = pkfma(wi1[2*q+1], hp1, p1);
        }
        #pragma unroll
        for (int q = 4; q < 8; ++q) {
            v4f hq = h4[q];
            v2f hp0 = __builtin_shufflevector(hq, hq, 0, 1);
            v2f hp1 = __builtin_shufflevector(hq, hq, 2, 3);
            p2 = pkfma(wi1[2*q],   hp0, p2);
            p3 = pkfma(wi1[2*q+1], hp1, p3);
        }
        float g1 = RED4(p0, p1, p2, p3);
        float act1 = fmaf(sc, __builtin_amdgcn_rcpf(1.0f + exp2f(kk * g1)), bb);
        if (wid == 0) ab1[l] = act1;           // i -> [m], f -> [32+m]
        __syncthreads();                        // B3

        // ---------------- S7: cell1 (wave1) ----------------
        if (wid == 1) {
            float ov = __shfl_xor(act1, 32);    // lanes<32: o[m]
            if (l < 32) {
                float iv = ab1[m], fv = ab1[32 + m];
                cst = fmaf(fv, cst, iv * act1);            // c1 = f*c1 + i*g
                float th = fmaf(2.0f, __builtin_amdgcn_rcpf(1.0f + exp2f(NL2E2 * cst)), -1.0f);
                hlast = ov * th;
                hcat[HID + m] = hlast;                     // h1_t
            }
        }
        __syncthreads();                        // B4
    }
#undef RED4

    // ---- final linear head: wave1 lanes<32 hold h1_{T-1}[m] ----
    if (wid == 1) {
        float q0 = (l < 32) ? (Wfc[m]       * hlast) : 0.0f;
        float q1 = (l < 32) ? (Wfc[HID + m] * hlast) : 0.0f;
        #pragma unroll
        for (int off = 16; off >= 1; off >>= 1) {
            q0 += __shfl_xor(q0, off);
            q1 += __shfl_xor(q1, off);
        }
        if (l == 0) {
            out[2 * b + 0] = q0 + bfc[0];
            out[2 * b + 1] = q1 + bfc[1];
        }
    }
}

extern "C" void kernel_launch(void* const* d_in, const int* in_sizes, int n_in,
                              void* d_out, int out_size, void* d_ws, size_t ws_size,
                              hipStream_t stream) {
    const float* x    = (const float*)d_in[0];
    const float* Wih0 = (const float*)d_in[1];
    const float* Whh0 = (const float*)d_in[2];
    const float* bih0 = (const float*)d_in[3];
    const float* bhh0 = (const float*)d_in[4];
    const float* Wih1 = (const float*)d_in[5];
    const float* Whh1 = (const float*)d_in[6];
    const float* bih1 = (const float*)d_in[7];
    const float* bhh1 = (const float*)d_in[8];
    const float* Wfc  = (const float*)d_in[9];
    const float* bfc  = (const float*)d_in[10];
    float* out = (float*)d_out;

    const int nb = in_sizes[0] / (T_LEN * INP);   // 2048 batch elements
    lstm2_2w<<<dim3(nb), dim3(128), 0, stream>>>(
        x, Wih0, Whh0, bih0, bhh0, Wih1, Whh1, bih1, bhh1, Wfc, bfc, out);
}

// Round 6
// 504.258 us; speedup vs baseline: 1.6310x; 1.6310x over previous
//
#include <hip/hip_runtime.h>

typedef float v2f __attribute__((ext_vector_type(2)));

#define T_LEN 512
#define INP 5
#define HID 32

__device__ __forceinline__ v2f pkfma(v2f a, v2f b, v2f c) {
    return __builtin_elementwise_fma(a, b, c);
}

// One wave per batch element (2048 blocks x 64). R3 bit-exact arithmetic;
// codegen-only changes: launch_bounds(64) [full 256-VGPR budget], v2f (b64)
// LDS h reads [no v4f->v2f unpack movs], float2 weight preloads.
__global__ __launch_bounds__(64) void lstm2_fused(
    const float* __restrict__ x,
    const float* __restrict__ Wih0, const float* __restrict__ Whh0,
    const float* __restrict__ bih0, const float* __restrict__ bhh0,
    const float* __restrict__ Wih1, const float* __restrict__ Whh1,
    const float* __restrict__ bih1, const float* __restrict__ bhh1,
    const float* __restrict__ Wfc,  const float* __restrict__ bfc,
    float* __restrict__ out)
{
    const int b = blockIdx.x;
    const int l = threadIdx.x;        // 0..63
    const int glo = l, ghi = l + 64;  // this lane's two gate rows (of 128)
    const bool isIG = (l < 32);       // lanes<32: (i,g); lanes>=32: (f,o)

    __shared__ __align__(16) float xs[T_LEN][8];   // 16 KB staged input
    __shared__ __align__(16) float h0s[HID];
    __shared__ __align__(16) float h1s[HID];

    // ---- stage x[b] into LDS, coalesced ----
    const float* xb = x + (size_t)b * (T_LEN * INP);
    for (int idx = l; idx < T_LEN * INP; idx += 64) {
        const int t = idx / INP;
        const int d = idx - t * INP;
        xs[t][d] = xb[idx];
    }

    // ---- weights register-resident as v2f over j-pairs (loaded as float2) ----
    v2f whh0_lo[16], whh0_hi[16], wih1_lo[16], wih1_hi[16], whh1_lo[16], whh1_hi[16];
#define LOADW(dst_lo, dst_hi, W) { \
    const v2f* rlo_ = (const v2f*)((W) + glo * HID); \
    const v2f* rhi_ = (const v2f*)((W) + ghi * HID); \
    _Pragma("unroll") \
    for (int q = 0; q < 16; ++q) { \
        dst_lo[q] = rlo_[q]; \
        dst_hi[q] = rhi_[q]; \
    } }
    LOADW(whh0_lo, whh0_hi, Whh0)
    LOADW(wih1_lo, wih1_hi, Wih1)
    LOADW(whh1_lo, whh1_hi, Whh1)
#undef LOADW

    v2f wxlo01, wxlo23, wxhi01, wxhi23;
    float wxlo4, wxhi4;
    {
        const float* rl = Wih0 + glo * INP;
        const float* rh = Wih0 + ghi * INP;
        wxlo01 = (v2f){rl[0], rl[1]}; wxlo23 = (v2f){rl[2], rl[3]}; wxlo4 = rl[4];
        wxhi01 = (v2f){rh[0], rh[1]}; wxhi23 = (v2f){rh[2], rh[3]}; wxhi4 = rh[4];
    }

    const float bias0_lo = bih0[glo] + bhh0[glo];
    const float bias0_hi = bih0[ghi] + bhh0[ghi];
    const float bias1_lo = bih1[glo] + bhh1[glo];
    const float bias1_hi = bih1[ghi] + bhh1[ghi];

    // activations: sigmoid(v) = rcp(1+exp2(-log2e*v)); tanh(v) = 2*rcp(1+exp2(-2log2e*v))-1
    const float NL2E  = -1.4426950408889634f;
    const float NL2E2 = -2.8853900817779268f;
    const float kk_hi = isIG ? NL2E2 : NL2E;    // g: tanh, o: sigmoid
    const float sc_hi = isIG ?  2.0f : 1.0f;
    const float bb_hi = isIG ? -1.0f : 0.0f;

    float c0 = 0.0f, c1 = 0.0f, h1last = 0.0f;
    if (l < HID) { h0s[l] = 0.0f; h1s[l] = 0.0f; }
    __syncthreads();

    const v2f* h02 = (const v2f*)h0s;   // 16 v2f
    const v2f* h12 = (const v2f*)h1s;

#define RED(a0, a1) ({ v2f s_ = (a0) + (a1); s_.x + s_.y; })

    for (int t = 0; t < T_LEN; ++t) {
        // ---- x_t from LDS (uniform broadcast reads) ----
        v2f xv01 = *(const v2f*)&xs[t][0];
        v2f xv23 = *(const v2f*)&xs[t][2];
        float x4 = xs[t][4];

        // ================= layer 0 =================
        v2f aL0 = pkfma(wxlo01, xv01, (v2f){bias0_lo, 0.0f});
        v2f aL1 = pkfma(wxlo23, xv23, (v2f){wxlo4 * x4, 0.0f});
        v2f aH0 = pkfma(wxhi01, xv01, (v2f){bias0_hi, 0.0f});
        v2f aH1 = pkfma(wxhi23, xv23, (v2f){wxhi4 * x4, 0.0f});
        #pragma unroll
        for (int r = 0; r < 8; ++r) {
            v2f hp0 = h02[2*r];                  // uniform ds_read_b64
            v2f hp1 = h02[2*r+1];
            aL0 = pkfma(whh0_lo[2*r],   hp0, aL0);
            aL1 = pkfma(whh0_lo[2*r+1], hp1, aL1);
            aH0 = pkfma(whh0_hi[2*r],   hp0, aH0);
            aH1 = pkfma(whh0_hi[2*r+1], hp1, aH1);
        }
        float gl = RED(aL0, aL1);
        float gh = RED(aH0, aH1);

        float actL = __builtin_amdgcn_rcpf(1.0f + exp2f(NL2E * gl));             // sigmoid
        float actH = fmaf(sc_hi, __builtin_amdgcn_rcpf(1.0f + exp2f(kk_hi * gh)), bb_hi);
        float actLs = __shfl_xor(actL, 32);
        float actHs = __shfl_xor(actH, 32);
        float i_ = isIG ? actL  : actLs;
        float f_ = isIG ? actLs : actL;
        float g_ = isIG ? actH  : actHs;
        float o_ = isIG ? actHs : actH;
        c0 = fmaf(f_, c0, i_ * g_);
        float th0 = fmaf(2.0f, __builtin_amdgcn_rcpf(1.0f + exp2f(NL2E2 * c0)), -1.0f);
        float h0new = o_ * th0;
        if (l < HID) h0s[l] = h0new;
        __syncthreads();

        // ================= layer 1 (single fused accumulation, R3 order) =================
        v2f bL0 = (v2f){bias1_lo, 0.0f}, bL1 = (v2f)0.0f;
        v2f bH0 = (v2f){bias1_hi, 0.0f}, bH1 = (v2f)0.0f;
        #pragma unroll
        for (int r = 0; r < 8; ++r) {
            v2f hp0 = h02[2*r];                  // h0_t (fresh)
            v2f hp1 = h02[2*r+1];
            bL0 = pkfma(wih1_lo[2*r],   hp0, bL0);
            bL1 = pkfma(wih1_lo[2*r+1], hp1, bL1);
            bH0 = pkfma(wih1_hi[2*r],   hp0, bH0);
            bH1 = pkfma(wih1_hi[2*r+1], hp1, bH1);
        }
        #pragma unroll
        for (int r = 0; r < 8; ++r) {
            v2f hp0 = h12[2*r];                  // h1_{t-1}
            v2f hp1 = h12[2*r+1];
            bL0 = pkfma(whh1_lo[2*r],   hp0, bL0);
            bL1 = pkfma(whh1_lo[2*r+1], hp1, bL1);
            bH0 = pkfma(whh1_hi[2*r],   hp0, bH0);
            bH1 = pkfma(whh1_hi[2*r+1], hp1, bH1);
        }
        float gl1 = RED(bL0, bL1);
        float gh1 = RED(bH0, bH1);

        float actL1 = __builtin_amdgcn_rcpf(1.0f + exp2f(NL2E * gl1));
        float actH1 = fmaf(sc_hi, __builtin_amdgcn_rcpf(1.0f + exp2f(kk_hi * gh1)), bb_hi);
        float actL1s = __shfl_xor(actL1, 32);
        float actH1s = __shfl_xor(actH1, 32);
        float i1 = isIG ? actL1  : actL1s;
        float f1 = isIG ? actL1s : actL1;
        float g1 = isIG ? actH1  : actH1s;
        float o1 = isIG ? actH1s : actH1;
        c1 = fmaf(f1, c1, i1 * g1);
        float th1 = fmaf(2.0f, __builtin_amdgcn_rcpf(1.0f + exp2f(NL2E2 * c1)), -1.0f);
        h1last = o1 * th1;
        if (l < HID) h1s[l] = h1last;
        __syncthreads();
    }
#undef RED

    // ---- final linear head ----
    const int m = l & 31;
    float p0 = isIG ? (Wfc[m]       * h1last) : 0.0f;
    float p1 = isIG ? (Wfc[HID + m] * h1last) : 0.0f;
    #pragma unroll
    for (int off = 32; off >= 1; off >>= 1) {
        p0 += __shfl_xor(p0, off);
        p1 += __shfl_xor(p1, off);
    }
    if (l == 0) {
        out[2 * b + 0] = p0 + bfc[0];
        out[2 * b + 1] = p1 + bfc[1];
    }
}

extern "C" void kernel_launch(void* const* d_in, const int* in_sizes, int n_in,
                              void* d_out, int out_size, void* d_ws, size_t ws_size,
                              hipStream_t stream) {
    const float* x    = (const float*)d_in[0];
    const float* Wih0 = (const float*)d_in[1];
    const float* Whh0 = (const float*)d_in[2];
    const float* bih0 = (const float*)d_in[3];
    const float* bhh0 = (const float*)d_in[4];
    const float* Wih1 = (const float*)d_in[5];
    const float* Whh1 = (const float*)d_in[6];
    const float* bih1 = (const float*)d_in[7];
    const float* bhh1 = (const float*)d_in[8];
    const float* Wfc  = (const float*)d_in[9];
    const float* bfc  = (const float*)d_in[10];
    float* out = (float*)d_out;

    const int nb = in_sizes[0] / (T_LEN * INP);   // 2048 batch elements
    lstm2_fused<<<dim3(nb), dim3(64), 0, stream>>>(
        x, Wih0, Whh0, bih0, bhh0, Wih1, Whh1, bih1, bhh1, Wfc, bfc, out);
}